// Round 1
// baseline (10699.165 us; speedup 1.0000x reference)
//
#include <hip/hip_runtime.h>

#define DIM 128
#define LEAKY 0.2f
#define N_NODES_C 200000
#define N_HE_C 50000

// One nnz handled by 32 consecutive lanes; each lane owns 4 consecutive floats.
// gather: src[gidx[k]] * vals[k]  -> atomic accumulate into dst[sidx[k]]
__global__ void scatter_step(const float* __restrict__ src,
                             const float* __restrict__ vals,
                             const int*   __restrict__ gidx,
                             const int*   __restrict__ sidx,
                             float*       __restrict__ dst,
                             int nnz) {
    long long t = (long long)blockIdx.x * blockDim.x + threadIdx.x;
    int k = (int)(t >> 5);
    if (k >= nnz) return;
    int q = ((int)t & 31) << 2;   // float offset within the 128-wide row

    int   g = gidx[k];
    int   s = sidx[k];
    float v = vals[k];

    const float4 e = *reinterpret_cast<const float4*>(src + (size_t)g * DIM + q);
    float* dp = dst + (size_t)s * DIM + q;

    unsafeAtomicAdd(dp + 0, e.x * v);
    unsafeAtomicAdd(dp + 1, e.y * v);
    unsafeAtomicAdd(dp + 2, e.z * v);
    unsafeAtomicAdd(dp + 3, e.w * v);
}

__global__ void leaky_inplace(float* __restrict__ out, int n4) {
    int t = blockIdx.x * blockDim.x + threadIdx.x;
    if (t >= n4) return;
    float4* p = reinterpret_cast<float4*>(out) + t;
    float4 x = *p;
    x.x = x.x >= 0.f ? x.x : LEAKY * x.x;
    x.y = x.y >= 0.f ? x.y : LEAKY * x.y;
    x.z = x.z >= 0.f ? x.z : LEAKY * x.z;
    x.w = x.w >= 0.f ? x.w : LEAKY * x.w;
    *p = x;
}

extern "C" void kernel_launch(void* const* d_in, const int* in_sizes, int n_in,
                              void* d_out, int out_size, void* d_ws, size_t ws_size,
                              hipStream_t stream) {
    const float* embs = (const float*)d_in[0];
    const float* vals = (const float*)d_in[1];
    const int*   rows = (const int*)d_in[2];
    const int*   cols = (const int*)d_in[3];
    const int nnz = in_sizes[1];

    float* he  = (float*)d_ws;                 // [N_HE_C, DIM] f32 = 25.6 MB
    float* out = (float*)d_out;                // [N_NODES_C, DIM] f32

    // Zero accumulators every call (harness does not re-poison between replays).
    hipMemsetAsync(he,  0, (size_t)N_HE_C   * DIM * sizeof(float), stream);
    hipMemsetAsync(out, 0, (size_t)N_NODES_C * DIM * sizeof(float), stream);

    long long nthreads = (long long)nnz * 32;
    dim3 blk(256);
    dim3 grd((unsigned)((nthreads + 255) / 256));

    // Step 1: he[c] += embs[r] * v
    scatter_step<<<grd, blk, 0, stream>>>(embs, vals, rows, cols, he, nnz);
    // Step 2: out[r] += he[c] * v
    scatter_step<<<grd, blk, 0, stream>>>(he, vals, cols, rows, out, nnz);

    // LeakyReLU in place
    int n4 = N_NODES_C * DIM / 4;
    leaky_inplace<<<(n4 + 255) / 256, 256, 0, stream>>>(out, n4);
}

// Round 2
// 1026.631 us; speedup vs baseline: 10.4216x; 10.4216x over previous
//
#include <hip/hip_runtime.h>

#define DIM 128
#define LEAKY 0.2f
#define N_NODES_C 200000
#define N_HE_C 50000

#define SCAN_B 256
#define SCAN_CHUNK 2048
#define PER_TH (SCAN_CHUNK / SCAN_B)   // 8

// ============================ CSR build ============================

__global__ void hist_kernel(const int* __restrict__ rows, const int* __restrict__ cols,
                            int nnz, int* __restrict__ rowCnt, int* __restrict__ colCnt) {
    int k = blockIdx.x * blockDim.x + threadIdx.x;
    if (k >= nnz) return;
    atomicAdd(&rowCnt[rows[k]], 1);
    atomicAdd(&colCnt[cols[k]], 1);
}

// exclusive scan, stage 1: per-block (2048 elems) scan + block sums
__global__ void scan_local(const int* __restrict__ in, int n,
                           int* __restrict__ out, int* __restrict__ bsums) {
    __shared__ int lds[SCAN_CHUNK];
    __shared__ int part[SCAN_B];
    int base = blockIdx.x * SCAN_CHUNK;
    for (int i = threadIdx.x; i < SCAN_CHUNK; i += SCAN_B) {
        int g = base + i;
        lds[i] = (g < n) ? in[g] : 0;
    }
    __syncthreads();
    int t0 = threadIdx.x * PER_TH;
    int local[PER_TH];
    int s = 0;
    #pragma unroll
    for (int j = 0; j < PER_TH; ++j) { local[j] = s; s += lds[t0 + j]; }
    part[threadIdx.x] = s;
    __syncthreads();
    for (int off = 1; off < SCAN_B; off <<= 1) {
        int x = part[threadIdx.x];
        int add = (threadIdx.x >= off) ? part[threadIdx.x - off] : 0;
        __syncthreads();
        part[threadIdx.x] = x + add;
        __syncthreads();
    }
    int texcl = (threadIdx.x == 0) ? 0 : part[threadIdx.x - 1];
    if (threadIdx.x == SCAN_B - 1) bsums[blockIdx.x] = part[SCAN_B - 1];
    #pragma unroll
    for (int j = 0; j < PER_TH; ++j) {
        int g = base + t0 + j;
        if (g < n) out[g] = texcl + local[j];
    }
}

// stage 2: scan the block sums (nb <= 256) into exclusive offsets, in place
__global__ void scan_sums(int* __restrict__ bsums, int nb) {
    __shared__ int lds[SCAN_B];
    int t = threadIdx.x;
    lds[t] = (t < nb) ? bsums[t] : 0;
    __syncthreads();
    for (int off = 1; off < SCAN_B; off <<= 1) {
        int x = lds[t];
        int add = (t >= off) ? lds[t - off] : 0;
        __syncthreads();
        lds[t] = x + add;
        __syncthreads();
    }
    if (t < nb) bsums[t] = (t == 0) ? 0 : lds[t - 1];
}

// stage 3: add block offsets; also write starts[n] = nnz
__global__ void scan_add(int* __restrict__ out, int n, const int* __restrict__ bsums, int total) {
    int g = blockIdx.x * blockDim.x + threadIdx.x;
    if (g < n) out[g] += bsums[g / SCAN_CHUNK];
    if (g == n) out[n] = total;
}

// scatter nnz entries into both CSRs as packed (index, value)
__global__ void scatter_build(const int* __restrict__ rows, const int* __restrict__ cols,
                              const float* __restrict__ vals, int nnz,
                              const int* __restrict__ rowStart, const int* __restrict__ colStart,
                              int* __restrict__ rowCur, int* __restrict__ colCur,
                              int2* __restrict__ rowPacked, int2* __restrict__ colPacked) {
    int k = blockIdx.x * blockDim.x + threadIdx.x;
    if (k >= nnz) return;
    int r = rows[k], c = cols[k];
    int vbits = __float_as_int(vals[k]);
    int pr = rowStart[r] + atomicAdd(&rowCur[r], 1);
    rowPacked[pr] = make_int2(c, vbits);
    int pc = colStart[c] + atomicAdd(&colCur[c], 1);
    colPacked[pc] = make_int2(r, vbits);
}

// ==================== segment gather-accumulate ====================
// One 64-lane wave per segment; lane owns 2 consecutive floats of the
// 128-wide row. Register accumulation, single coalesced 512B write.
template <bool RELU>
__global__ void seg_accum(const int* __restrict__ start, const int2* __restrict__ packed,
                          const float* __restrict__ src, float* __restrict__ dst, int nseg) {
    int wid = (int)((blockIdx.x * (unsigned)blockDim.x + threadIdx.x) >> 6);
    int lane = threadIdx.x & 63;
    if (wid >= nseg) return;
    int s = start[wid];
    int e = start[wid + 1];
    const float2* src2 = reinterpret_cast<const float2*>(src);
    float ax = 0.f, ay = 0.f;
    int j = s;
    for (; j + 4 <= e; j += 4) {
        int2 p0 = packed[j + 0];
        int2 p1 = packed[j + 1];
        int2 p2 = packed[j + 2];
        int2 p3 = packed[j + 3];
        float2 e0 = src2[(size_t)p0.x * 64 + lane];
        float2 e1 = src2[(size_t)p1.x * 64 + lane];
        float2 e2 = src2[(size_t)p2.x * 64 + lane];
        float2 e3 = src2[(size_t)p3.x * 64 + lane];
        float v0 = __int_as_float(p0.y), v1 = __int_as_float(p1.y);
        float v2 = __int_as_float(p2.y), v3 = __int_as_float(p3.y);
        ax += e0.x * v0; ay += e0.y * v0;
        ax += e1.x * v1; ay += e1.y * v1;
        ax += e2.x * v2; ay += e2.y * v2;
        ax += e3.x * v3; ay += e3.y * v3;
    }
    for (; j < e; ++j) {
        int2 p = packed[j];
        float v = __int_as_float(p.y);
        float2 ev = src2[(size_t)p.x * 64 + lane];
        ax += ev.x * v; ay += ev.y * v;
    }
    if (RELU) {
        ax = ax >= 0.f ? ax : LEAKY * ax;
        ay = ay >= 0.f ? ay : LEAKY * ay;
    }
    float2 r2 = make_float2(ax, ay);
    reinterpret_cast<float2*>(dst)[(size_t)wid * 64 + lane] = r2;
}

// ==================== fallback (atomic) path ====================

__global__ void scatter_step(const float* __restrict__ src, const float* __restrict__ vals,
                             const int* __restrict__ gidx, const int* __restrict__ sidx,
                             float* __restrict__ dst, int nnz) {
    long long t = (long long)blockIdx.x * blockDim.x + threadIdx.x;
    int k = (int)(t >> 5);
    if (k >= nnz) return;
    int q = ((int)t & 31) << 2;
    int g = gidx[k];
    int s = sidx[k];
    float v = vals[k];
    const float4 e = *reinterpret_cast<const float4*>(src + (size_t)g * DIM + q);
    float* dp = dst + (size_t)s * DIM + q;
    unsafeAtomicAdd(dp + 0, e.x * v);
    unsafeAtomicAdd(dp + 1, e.y * v);
    unsafeAtomicAdd(dp + 2, e.z * v);
    unsafeAtomicAdd(dp + 3, e.w * v);
}

__global__ void leaky_inplace(float* __restrict__ out, int n4) {
    int t = blockIdx.x * blockDim.x + threadIdx.x;
    if (t >= n4) return;
    float4* p = reinterpret_cast<float4*>(out) + t;
    float4 x = *p;
    x.x = x.x >= 0.f ? x.x : LEAKY * x.x;
    x.y = x.y >= 0.f ? x.y : LEAKY * x.y;
    x.z = x.z >= 0.f ? x.z : LEAKY * x.z;
    x.w = x.w >= 0.f ? x.w : LEAKY * x.w;
    *p = x;
}

// ============================ launch ============================

extern "C" void kernel_launch(void* const* d_in, const int* in_sizes, int n_in,
                              void* d_out, int out_size, void* d_ws, size_t ws_size,
                              hipStream_t stream) {
    const float* embs = (const float*)d_in[0];
    const float* vals = (const float*)d_in[1];
    const int*   rows = (const int*)d_in[2];
    const int*   cols = (const int*)d_in[3];
    const int nnz = in_sizes[1];
    float* out = (float*)d_out;

    // ---- workspace layout (256B aligned) ----
    char* ws = (char*)d_ws;
    size_t off = 0;
    auto alloc = [&](size_t bytes) -> char* {
        char* p = ws + off;
        off = (off + bytes + 255) & ~(size_t)255;
        return p;
    };
    float* he       = (float*)alloc((size_t)N_HE_C * DIM * sizeof(float));     // 25.6 MB
    int*   colStart = (int*)  alloc((size_t)(N_HE_C + 1) * sizeof(int));
    int*   rowStart = (int*)  alloc((size_t)(N_NODES_C + 1) * sizeof(int));
    int*   colCnt   = (int*)  alloc((size_t)N_HE_C * sizeof(int));
    int*   rowCnt   = (int*)  alloc((size_t)N_NODES_C * sizeof(int));
    int*   colCur   = (int*)  alloc((size_t)N_HE_C * sizeof(int));
    int*   rowCur   = (int*)  alloc((size_t)N_NODES_C * sizeof(int));
    int*   bsumsC   = (int*)  alloc(4096 * sizeof(int));
    int*   bsumsR   = (int*)  alloc(4096 * sizeof(int));
    int2*  colPacked= (int2*) alloc((size_t)nnz * sizeof(int2));               // 25.6 MB
    int2*  rowPacked= (int2*) alloc((size_t)nnz * sizeof(int2));               // 25.6 MB
    size_t required = off;

    if (ws_size < required) {
        // -------- fallback: atomic path (R1, proven) --------
        hipMemsetAsync(he,  0, (size_t)N_HE_C * DIM * sizeof(float), stream);
        hipMemsetAsync(out, 0, (size_t)N_NODES_C * DIM * sizeof(float), stream);
        long long nthreads = (long long)nnz * 32;
        dim3 grd((unsigned)((nthreads + 255) / 256));
        scatter_step<<<grd, 256, 0, stream>>>(embs, vals, rows, cols, he, nnz);
        scatter_step<<<grd, 256, 0, stream>>>(he, vals, cols, rows, out, nnz);
        int n4 = N_NODES_C * DIM / 4;
        leaky_inplace<<<(n4 + 255) / 256, 256, 0, stream>>>(out, n4);
        return;
    }

    // ---- zero counters & cursors ----
    hipMemsetAsync(colCnt, 0, (size_t)N_HE_C * sizeof(int), stream);
    hipMemsetAsync(rowCnt, 0, (size_t)N_NODES_C * sizeof(int), stream);
    hipMemsetAsync(colCur, 0, (size_t)N_HE_C * sizeof(int), stream);
    hipMemsetAsync(rowCur, 0, (size_t)N_NODES_C * sizeof(int), stream);

    // ---- histogram ----
    int gb = (nnz + 255) / 256;
    hist_kernel<<<gb, 256, 0, stream>>>(rows, cols, nnz, rowCnt, colCnt);

    // ---- exclusive scans (counts -> starts) ----
    {
        int nbC = (N_HE_C + SCAN_CHUNK - 1) / SCAN_CHUNK;      // 25
        scan_local<<<nbC, SCAN_B, 0, stream>>>(colCnt, N_HE_C, colStart, bsumsC);
        scan_sums<<<1, SCAN_B, 0, stream>>>(bsumsC, nbC);
        scan_add<<<(N_HE_C + 1 + 255) / 256, 256, 0, stream>>>(colStart, N_HE_C, bsumsC, nnz);

        int nbR = (N_NODES_C + SCAN_CHUNK - 1) / SCAN_CHUNK;   // 98
        scan_local<<<nbR, SCAN_B, 0, stream>>>(rowCnt, N_NODES_C, rowStart, bsumsR);
        scan_sums<<<1, SCAN_B, 0, stream>>>(bsumsR, nbR);
        scan_add<<<(N_NODES_C + 1 + 255) / 256, 256, 0, stream>>>(rowStart, N_NODES_C, bsumsR, nnz);
    }

    // ---- scatter entries into both CSRs ----
    scatter_build<<<gb, 256, 0, stream>>>(rows, cols, vals, nnz, rowStart, colStart,
                                          rowCur, colCur, rowPacked, colPacked);

    // ---- pass 1: he[e] = sum over entries (rows idx) of embs[r] * v ----
    {
        int waves = N_HE_C;
        int blocks = (waves + 3) / 4;   // 4 waves / 256-thread block
        seg_accum<false><<<blocks, 256, 0, stream>>>(colStart, colPacked, embs, he, N_HE_C);
    }
    // ---- pass 2 (+LeakyReLU): out[n] = sum over entries (cols idx) of he[c] * v ----
    {
        int waves = N_NODES_C;
        int blocks = (waves + 3) / 4;
        seg_accum<true><<<blocks, 256, 0, stream>>>(rowStart, rowPacked, he, out, N_NODES_C);
    }
}